// Round 11
// baseline (554.082 us; speedup 1.0000x reference)
//
#include <hip/hip_runtime.h>
#include <cstdint>
#include <cstddef>

#define SEQ     2048
#define NBATCH  2
#define BL      (NBATCH*SEQ)     // 4096
#define DMODEL  2048
#define DINNER  4096
#define DSTATE  128
#define HEADDIM 64
#define NHEADS  64
#define DXBC    4352
#define DPROJ   8512
#define NPAD    8704             // padded D_IN_PROJ (34*256)
#define NCHUNK  16
#define CHUNKL  128

typedef __bf16 bf16x8_t __attribute__((ext_vector_type(8)));
typedef float f32x4_t __attribute__((ext_vector_type(4)));
typedef unsigned short u16x8_t __attribute__((ext_vector_type(8)));
typedef unsigned short u16x4_t __attribute__((ext_vector_type(4)));
typedef __attribute__((address_space(1))) unsigned int as1_u32;
typedef __attribute__((address_space(3))) unsigned int as3_u32;

__device__ __forceinline__ unsigned short f2bf(float f) {
  unsigned u = __builtin_bit_cast(unsigned, f);
  u += 0x7FFFu + ((u >> 16) & 1u);
  return (unsigned short)(u >> 16);
}
__device__ __forceinline__ float bf2f(unsigned short h) {
  unsigned u = ((unsigned)h) << 16;
  return __builtin_bit_cast(float, u);
}
__device__ __forceinline__ void gload16(const void* g, void* l) {
  __builtin_amdgcn_global_load_lds((const as1_u32*)g, (as3_u32*)l, 16, 0, 0);
}
__device__ __forceinline__ f32x4_t mfma16(u16x8_t a, u16x8_t b, f32x4_t c) {
  return __builtin_amdgcn_mfma_f32_16x16x32_bf16(
      __builtin_bit_cast(bf16x8_t, a), __builtin_bit_cast(bf16x8_t, b), c, 0, 0, 0);
}
__device__ __forceinline__ float siluf(float x) { return x / (1.f + __expf(-x)); }

// -------- merged convert: u -> u_bf  |  W_in -> win_bf (zero-padded rows) --------
#define GB_U   (BL * DMODEL / 4 / 256)          // 8192
#define GB_WIN (NPAD * DMODEL / 4 / 256)        // 17408
__global__ __launch_bounds__(256) void cvt_uw_kernel(const float* __restrict__ u,
                                                     unsigned short* __restrict__ u_bf,
                                                     const float* __restrict__ W_in,
                                                     unsigned short* __restrict__ win_bf) {
  int blk = blockIdx.x;
  if (blk < GB_U) {
    int idx = (blk * 256 + threadIdx.x) * 4;
    float4 v = *(const float4*)&u[idx];
    u16x4_t o; o[0] = f2bf(v.x); o[1] = f2bf(v.y); o[2] = f2bf(v.z); o[3] = f2bf(v.w);
    *(u16x4_t*)&u_bf[idx] = o;
  } else {
    int idx = ((blk - GB_U) * 256 + threadIdx.x) * 4;
    int e = idx / DMODEL;
    u16x4_t o;
    if (e < DPROJ) {
      float4 v = *(const float4*)&W_in[idx];
      o[0] = f2bf(v.x); o[1] = f2bf(v.y); o[2] = f2bf(v.z); o[3] = f2bf(v.w);
    } else {
      o[0] = 0; o[1] = 0; o[2] = 0; o[3] = 0;
    }
    *(u16x4_t*)&win_bf[idx] = o;
  }
}

// ======== GEMM1: 8-phase m201-style template. 256x256 tile, BK=64, 8 waves ========
// C[M][N] = A[M][K]*B[N][K]^T bf16. 2 K-tile LDS dbuf (128 KiB). Per iteration
// (2 K-tiles) 8 phases: {ds_read quadrant, stage 1 half-tile, barrier, lgkm(0),
// setprio MFMA x16, barrier}. Counted vmcnt(4) only at P4/P8. Half staged one
// closing-barrier after its last reader: B halves P3/P4/P7/P8, A halves P5/P6/
// P1'/P2'. Swizzle: 128B rows, slot ^= row&7 (involution on gload src + read).
template <bool BF16OUT>
__global__ __launch_bounds__(512, 1) void gemm8p_kernel(const unsigned short* __restrict__ A,
                                                        const unsigned short* __restrict__ B,
                                                        void* __restrict__ Cp,
                                                        int M, int N, int K, int gx) {
  __shared__ __attribute__((aligned(16))) char lds[131072];
  const int nwg = gridDim.x;
  const int q8 = nwg >> 3;
  const int lid = blockIdx.x;
  const int newid = (lid & 7) * q8 + (lid >> 3);     // bijective XCD chunking
  const int band = newid / (gx * 4);
  const int idx  = newid % (gx * 4);
  const int n0 = (idx >> 2) * 256;
  const int m0 = (band * 4 + (idx & 3)) * 256;
  const int t = threadIdx.x, lane = t & 63, w = t >> 6;
  const int wm = w >> 2, wn = w & 3;                 // 2 x 4 waves
  const int NK = K >> 6;                             // 64-wide K tiles
  const int NT = NK >> 1;                            // iterations (2 tiles each)

  f32x4_t acc[8][4];
#pragma unroll
  for (int i = 0; i < 8; ++i)
#pragma unroll
    for (int j = 0; j < 4; ++j) acc[i][j] = (f32x4_t){0.f, 0.f, 0.f, 0.f};

  // half: 0=A.h0(rows 0-127) 1=A.h1 2=B.h0 3=B.h1 ; 16KB each, 2 gloads/thread-set
  auto stage_half = [&](int tile, int half) {
    if (tile >= NK) return;
    const bool isB = half >= 2;
    const int hh = half & 1;
    const unsigned short* G = isB ? B : A;
    const int g0 = (isB ? n0 : m0) + hh * 128;
    const int k0 = tile << 6;
    char* base = lds + (tile & 1) * 65536 + (isB ? 32768 : 0) + hh * 16384;
#pragma unroll
    for (int i = 0; i < 2; ++i) {
      int o = i * 8192 + t * 16;                     // 0..16383
      int row = o >> 7;                              // 0..127
      int sl  = (o >> 4) & 7;                        // physical 16B slot
      gload16(&G[(size_t)(g0 + row) * K + k0 + ((sl ^ (row & 7)) << 3)], base + o);
    }
  };
  auto rdA = [&](int buf, int mr, int kk) -> u16x8_t {
    int row = wm * 128 + mr * 16 + (lane & 15);
    int sl = kk * 4 + (lane >> 4);
    int byte = buf * 65536 + row * 128 + (((sl ^ (row & 7))) << 4);
    return *(const u16x8_t*)(lds + byte);
  };
  auto rdB = [&](int buf, int nr, int kk) -> u16x8_t {
    int row = wn * 64 + nr * 16 + (lane & 15);
    int sl = kk * 4 + (lane >> 4);
    int byte = buf * 65536 + 32768 + row * 128 + (((sl ^ (row & 7))) << 4);
    return *(const u16x8_t*)(lds + byte);
  };

  u16x8_t af[4][2], bf[4][2];

#define PH_SYNC() do { __builtin_amdgcn_s_barrier(); \
    asm volatile("s_waitcnt lgkmcnt(0)" ::: "memory"); \
    __builtin_amdgcn_sched_barrier(0); } while (0)
#define PH_END() __builtin_amdgcn_s_barrier()

  auto mm = [&](int mrBase, int nrBase) {
    __builtin_amdgcn_s_setprio(1);
#pragma unroll
    for (int m = 0; m < 4; ++m)
#pragma unroll
      for (int n = 0; n < 2; ++n) {
        acc[mrBase + m][nrBase + n] = mfma16(af[m][0], bf[nrBase + n][0], acc[mrBase + m][nrBase + n]);
        acc[mrBase + m][nrBase + n] = mfma16(af[m][1], bf[nrBase + n][1], acc[mrBase + m][nrBase + n]);
      }
    __builtin_amdgcn_s_setprio(0);
  };

  // prologue: tile0 all 4 halves + tile1 B halves (12 loads); tile0 must land
  stage_half(0, 0); stage_half(0, 1); stage_half(0, 2); stage_half(0, 3);
  stage_half(1, 2); stage_half(1, 3);
  asm volatile("s_waitcnt vmcnt(4)" ::: "memory");
  __builtin_amdgcn_s_barrier();

  for (int j = 0; j < NT; ++j) {
    const bool last = (j == NT - 1);
    const int t1 = 2 * j + 1;
    // ---- P1: read A(mr0-3)+B(nr0-1) buf0; stage buf1.A.h0 (tile t1)
#pragma unroll
    for (int m = 0; m < 4; ++m) { af[m][0] = rdA(0, m, 0); af[m][1] = rdA(0, m, 1); }
#pragma unroll
    for (int n = 0; n < 2; ++n) { bf[n][0] = rdB(0, n, 0); bf[n][1] = rdB(0, n, 1); }
    stage_half(t1, 0);
    PH_SYNC(); mm(0, 0); PH_END();
    // ---- P2: read B(nr2-3) buf0; stage buf1.A.h1
    bf[2][0] = rdB(0, 2, 0); bf[2][1] = rdB(0, 2, 1);
    bf[3][0] = rdB(0, 3, 0); bf[3][1] = rdB(0, 3, 1);
    stage_half(t1, 1);
    PH_SYNC(); mm(0, 2); PH_END();
    // ---- P3: read A(mr4-7) buf0; stage buf0.B.h0 (tile t0+2)
#pragma unroll
    for (int m = 0; m < 4; ++m) { af[m][0] = rdA(0, 4 + m, 0); af[m][1] = rdA(0, 4 + m, 1); }
    stage_half(2 * j + 2, 2);
    PH_SYNC(); mm(4, 0); PH_END();
    // ---- P4: stage buf0.B.h1; vmcnt guards buf1 (tile t1) before P5
    stage_half(2 * j + 2, 3);
    if (!last) asm volatile("s_waitcnt vmcnt(4)" ::: "memory");
    else       asm volatile("s_waitcnt vmcnt(0)" ::: "memory");
    PH_SYNC(); mm(4, 2); PH_END();
    // ---- P5: read A(mr0-3)+B(nr0-1) buf1; stage buf0.A.h0 (tile t0+2)
#pragma unroll
    for (int m = 0; m < 4; ++m) { af[m][0] = rdA(1, m, 0); af[m][1] = rdA(1, m, 1); }
#pragma unroll
    for (int n = 0; n < 2; ++n) { bf[n][0] = rdB(1, n, 0); bf[n][1] = rdB(1, n, 1); }
    stage_half(2 * j + 2, 0);
    PH_SYNC(); mm(0, 0); PH_END();
    // ---- P6: read B(nr2-3) buf1; stage buf0.A.h1
    bf[2][0] = rdB(1, 2, 0); bf[2][1] = rdB(1, 2, 1);
    bf[3][0] = rdB(1, 3, 0); bf[3][1] = rdB(1, 3, 1);
    stage_half(2 * j + 2, 1);
    PH_SYNC(); mm(0, 2); PH_END();
    // ---- P7: read A(mr4-7) buf1; stage buf1.B.h0 (tile t1+2)
#pragma unroll
    for (int m = 0; m < 4; ++m) { af[m][0] = rdA(1, 4 + m, 0); af[m][1] = rdA(1, 4 + m, 1); }
    stage_half(2 * j + 3, 2);
    PH_SYNC(); mm(4, 0); PH_END();
    // ---- P8: stage buf1.B.h1; vmcnt guards buf0 (tile t0+2) before next P1
    stage_half(2 * j + 3, 3);
    if (!last) asm volatile("s_waitcnt vmcnt(4)" ::: "memory");
    PH_SYNC(); mm(4, 2); PH_END();
  }
#undef PH_SYNC
#undef PH_END

  // epilogue (same verified mapping as R4)
#pragma unroll
  for (int mr = 0; mr < 8; ++mr) {
    const int mbase = m0 + wm * 128 + mr * 16 + (lane >> 4) * 4;
#pragma unroll
    for (int nr = 0; nr < 4; ++nr) {
      const int n = n0 + wn * 64 + nr * 16 + (lane & 15);
#pragma unroll
      for (int r = 0; r < 4; ++r) {
        if (BF16OUT) ((unsigned short*)Cp)[(size_t)(mbase + r) * N + n] = f2bf(acc[mr][nr][r]);
        else         ((float*)Cp)[(size_t)(mbase + r) * N + n] = acc[mr][nr][r];
      }
    }
  }
}

// ---------------- GEMM (R4 schedule, kept for GEMM2) ----------------
template <int WM, bool BF16OUT>
__global__ __launch_bounds__(512, 2) void gemm256_kernel(const unsigned short* __restrict__ A,
                                                         const unsigned short* __restrict__ B,
                                                         void* __restrict__ Cp,
                                                         int M, int N, int K, int gx) {
  constexpr int BM  = 32 * WM;
  constexpr int AUB = BM * 64;
  constexpr int BUB = 16384;
  constexpr int BUF = AUB + BUB;
  constexpr int LA  = AUB / 8192;
  constexpr int LB  = 2;
  constexpr int LT  = LA + LB;
  __shared__ __attribute__((aligned(16))) char lds[4 * BUF];

  const int nwg = gridDim.x;
  const int q8 = nwg >> 3;
  const int lid = blockIdx.x;
  const int newid = (lid & 7) * q8 + (lid >> 3);
  const int band = newid / (gx * 4);
  const int idx  = newid % (gx * 4);
  const int n0 = (idx >> 2) * 256;
  const int m0 = (band * 4 + (idx & 3)) * BM;

  const int t = threadIdx.x, lane = t & 63, w = t >> 6;
  const int wm = w >> 2, wn = w & 3;
  const int NK = K >> 5;
  const int kslot = (lane >> 4) * 16;

  f32x4_t acc[WM][4];
#pragma unroll
  for (int i = 0; i < WM; ++i)
#pragma unroll
    for (int j = 0; j < 4; ++j) acc[i][j] = (f32x4_t){0.f, 0.f, 0.f, 0.f};

  auto stage_unit = [&](int u) {
    if (u >= 2 * NK) return;
    const int Tt = u >> 1;
    char* base = lds + (Tt & 3) * BUF + ((u & 1) ? AUB : 0);
    const unsigned short* G = (u & 1) ? B : A;
    const int g0 = (u & 1) ? n0 : m0;
    const int k0 = Tt << 5;
    if (u & 1) {
#pragma unroll
      for (int i = 0; i < LB; ++i) {
        int o = i * 8192 + t * 16;
        int row = o >> 6;
        int cb = (o & 63) ^ (((row >> 1) & 3) << 4);
        gload16(&G[(size_t)(g0 + row) * K + k0 + (cb >> 1)], base + o);
      }
    } else {
#pragma unroll
      for (int i = 0; i < LA; ++i) {
        int o = i * 8192 + t * 16;
        int row = o >> 6;
        int cb = (o & 63) ^ (((row >> 1) & 3) << 4);
        gload16(&G[(size_t)(g0 + row) * K + k0 + (cb >> 1)], base + o);
      }
    }
  };
  auto rdA = [&](int bq, int mr) -> u16x8_t {
    int row = wm * (BM / 2) + mr * 16 + (lane & 15);
    int byte = bq * BUF + row * 64 + (kslot ^ (((row >> 1) & 3) << 4));
    return *(const u16x8_t*)(lds + byte);
  };
  auto rdB = [&](int bq, int nr) -> u16x8_t {
    int row = wn * 64 + nr * 16 + (lane & 15);
    int byte = bq * BUF + AUB + row * 64 + (kslot ^ (((row >> 1) & 3) << 4));
    return *(const u16x8_t*)(lds + byte);
  };

#pragma unroll
  for (int u = 0; u < 6; ++u) stage_unit(u);

  for (int T = 0; T < NK; ++T) {
    const int bq = T & 3;
    if (T <= NK - 3)      { if constexpr (LT == 4) asm volatile("s_waitcnt vmcnt(8)" ::: "memory");
                            else                   asm volatile("s_waitcnt vmcnt(6)" ::: "memory"); }
    else if (T == NK - 2) { if constexpr (LT == 4) asm volatile("s_waitcnt vmcnt(4)" ::: "memory");
                            else                   asm volatile("s_waitcnt vmcnt(3)" ::: "memory"); }
    else                  asm volatile("s_waitcnt vmcnt(0)" ::: "memory");
    __builtin_amdgcn_s_barrier();
    asm volatile("" ::: "memory");
    __builtin_amdgcn_sched_barrier(0);

    u16x8_t af[WM], bfr[4];
#pragma unroll
    for (int mr = 0; mr < WM; ++mr) af[mr] = rdA(bq, mr);
    bfr[0] = rdB(bq, 0);
    bfr[1] = rdB(bq, 1);
    stage_unit(2 * T + 6);
    __builtin_amdgcn_s_setprio(1);
#pragma unroll
    for (int mr = 0; mr < WM; ++mr) {
      acc[mr][0] = mfma16(af[mr], bfr[0], acc[mr][0]);
      acc[mr][1] = mfma16(af[mr], bfr[1], acc[mr][1]);
    }
    __builtin_amdgcn_s_setprio(0);
    bfr[2] = rdB(bq, 2);
    bfr[3] = rdB(bq, 3);
    stage_unit(2 * T + 7);
    __builtin_amdgcn_s_setprio(1);
#pragma unroll
    for (int mr = 0; mr < WM; ++mr) {
      acc[mr][2] = mfma16(af[mr], bfr[2], acc[mr][2]);
      acc[mr][3] = mfma16(af[mr], bfr[3], acc[mr][3]);
    }
    __builtin_amdgcn_s_setprio(0);
  }

#pragma unroll
  for (int mr = 0; mr < WM; ++mr) {
    const int mbase = m0 + wm * (BM / 2) + mr * 16 + (lane >> 4) * 4;
#pragma unroll
    for (int nr = 0; nr < 4; ++nr) {
      const int n = n0 + wn * 64 + nr * 16 + (lane & 15);
#pragma unroll
      for (int r = 0; r < 4; ++r) {
        if (BF16OUT) ((unsigned short*)Cp)[(size_t)(mbase + r) * N + n] = f2bf(acc[mr][nr][r]);
        else         ((float*)Cp)[(size_t)(mbase + r) * N + n] = acc[mr][nr][r];
      }
    }
  }
}

// -------- merged post-GEMM1: W_out convert | conv+silu | dt softplus+cumsum --------
#define GB_WOUT (DMODEL * DINNER / 4 / 256)     // 8192
#define GB_CONV (BL * (DXBC / 8) / 256)         // 8704
#define GB_DT   (NBATCH * NHEADS * NCHUNK / 2)  // 1024 (2 chunks/block)
__global__ __launch_bounds__(256) void postg1_kernel(const float* __restrict__ W_out,
                                                     unsigned short* __restrict__ wout_bf,
                                                     const unsigned short* __restrict__ zx,
                                                     const float* __restrict__ conv_w,
                                                     const float* __restrict__ conv_b,
                                                     unsigned short* __restrict__ xc,
                                                     const float* __restrict__ dt_bias,
                                                     const float* __restrict__ A_log,
                                                     float* __restrict__ dt_soft,
                                                     float* __restrict__ Acs,
                                                     float* __restrict__ cdecay) {
  __shared__ float sbuf[256];
  int blk = blockIdx.x;
  int t = threadIdx.x;
  if (blk < GB_WOUT) {
    int idx = (blk * 256 + t) * 4;
    float4 v = *(const float4*)&W_out[idx];
    u16x4_t o; o[0] = f2bf(v.x); o[1] = f2bf(v.y); o[2] = f2bf(v.z); o[3] = f2bf(v.w);
    *(u16x4_t*)&wout_bf[idx] = o;
  } else if (blk < GB_WOUT + GB_CONV) {
    int idx = (blk - GB_WOUT) * 256 + t;
    int e8 = (idx % (DXBC / 8)) * 8;
    int bl = idx / (DXBC / 8);
    int l = bl % SEQ, b = bl / SEQ;
    float acc[8];
#pragma unroll
    for (int j = 0; j < 8; ++j) acc[j] = conv_b[e8 + j];
    const unsigned short* zrow = zx + (size_t)b * SEQ * NPAD + DINNER + e8;
#pragma unroll
    for (int wi = 0; wi < 4; ++wi) {
      int ll = l - 3 + wi;
      if (ll >= 0) {
        u16x8_t v = *(const u16x8_t*)(zrow + (size_t)ll * NPAD);
#pragma unroll
        for (int j = 0; j < 8; ++j) acc[j] += bf2f(v[j]) * conv_w[(e8 + j) * 4 + wi];
      }
    }
    u16x8_t o;
#pragma unroll
    for (int j = 0; j < 8; ++j) o[j] = f2bf(siluf(acc[j]));
    *(u16x8_t*)(xc + (size_t)bl * DXBC + e8) = o;
  } else {
    int id = (blk - GB_WOUT - GB_CONV) * 2 + (t >> 7);
    int i = t & 127;
    int c = id & 15, h = (id >> 4) & 63, b = id >> 10;
    int l = c * CHUNKL + i;
    float raw = bf2f(zx[((size_t)b * SEQ + l) * NPAD + (DINNER + DXBC) + h]) + dt_bias[h];
    float dt = (raw > 20.f) ? raw : log1pf(__expf(raw));
    dt_soft[((size_t)b * 64 + h) * SEQ + l] = dt;
    float A = -__expf(A_log[h]);
    float* sb = sbuf + (t >> 7) * 128;
    sb[i] = dt * A;
    __syncthreads();
    for (int ofs = 1; ofs < 128; ofs <<= 1) {
      float v = (i >= ofs) ? sb[i - ofs] : 0.f;
      __syncthreads();
      sb[i] += v;
      __syncthreads();
    }
    float cs = sb[i];
    Acs[(((size_t)b * 64 + h) * 16 + c) * 128 + i] = cs;
    if (i == 127) cdecay[((size_t)b * 64 + h) * 16 + c] = __expf(cs);
  }
}

// -------- merged xdt^T builder | B transpose --------
#define GB_XDT (NBATCH * NHEADS * NCHUNK)       // 2048
__global__ __launch_bounds__(256) void xdtbtr_kernel(const unsigned short* __restrict__ xc,
                                                     const float* __restrict__ dt_soft,
                                                     unsigned short* __restrict__ xdtT,
                                                     unsigned short* __restrict__ BT) {
  __shared__ __attribute__((aligned(16))) char smem[33536];
  int blk = blockIdx.x;
  int t = threadIdx.x;
  if (blk < GB_XDT) {
    int lt = blk & 15, h = (blk >> 4) & 63, b = blk >> 10;
    unsigned short (*tile)[66] = (unsigned short(*)[66])smem;
    float* dts = (float*)(smem + 16896);
    const unsigned short* xg = xc + ((size_t)b * SEQ + lt * 128) * DXBC + h * 64;
#pragma unroll
    for (int k = 0; k < 32; ++k) {
      int idx = t + k * 256;
      int row = idx >> 6, col = idx & 63;
      tile[row][col] = xg[(size_t)row * DXBC + col];
    }
    if (t < 128) dts[t] = dt_soft[((size_t)b * 64 + h) * SEQ + lt * 128 + t];
    __syncthreads();
    unsigned short* xo = xdtT + (((size_t)b * 64 + h) * 64) * SEQ + lt * 128;
#pragma unroll
    for (int k = 0; k < 32; ++k) {
      int idx = t + k * 256;
      int p = idx >> 7, j = idx & 127;
      xo[(size_t)p * SEQ + j] = f2bf(bf2f(tile[j][p]) * dts[j]);
    }
  } else {
    int bb = blk - GB_XDT;
    int lt = bb & 15, b = bb >> 4;
    unsigned short (*tile)[129] = (unsigned short(*)[129])smem;
    const unsigned short* src = xc + ((size_t)b * SEQ + lt * 128) * DXBC + DINNER;
#pragma unroll
    for (int k = 0; k < 64; ++k) {
      int idx = t + k * 256;
      int j = idx >> 7, n = idx & 127;
      tile[j][n] = src[(size_t)j * DXBC + n];
    }
    __syncthreads();
    unsigned short* dst = BT + (size_t)b * 128 * SEQ + lt * 128;
#pragma unroll
    for (int k = 0; k < 64; ++k) {
      int idx = t + k * 256;
      int n = idx >> 7, j = idx & 127;
      dst[(size_t)n * SEQ + j] = tile[j][n];
    }
  }
}

// -------- SSD per-chunk states (bf16 out): states[b][c][h][p][n] --------
__global__ __launch_bounds__(256) void ssd_states_kernel(const unsigned short* __restrict__ BT,
                                                         const unsigned short* __restrict__ xdtT,
                                                         const float* __restrict__ Acs,
                                                         unsigned short* __restrict__ states) {
  int blk = blockIdx.x;
  int h = blk & 63, c = (blk >> 6) & 15, b = blk >> 10;
  __shared__ unsigned short BTs[128 * 128];
  __shared__ unsigned short xs[64 * 128];
  __shared__ float dec[128];
  int t = threadIdx.x, lane = t & 63, w = t >> 6, wr = w >> 1, wc = w & 1;
  int srow = t >> 4, scol = (t & 15) * 8;
  const unsigned short* BTb = BT + (size_t)b * 128 * SEQ + c * 128;
#pragma unroll
  for (int s = 0; s < 8; ++s) {
    int r = s * 16 + srow;
    gload16(&BTb[(size_t)r * SEQ + scol], &BTs[r * 128 + scol]);
  }
  const unsigned short* xb = xdtT + (((size_t)b * 64 + h) * 64) * SEQ + c * 128;
#pragma unroll
  for (int s = 0; s < 4; ++s) {
    int r = s * 16 + srow;
    gload16(&xb[(size_t)r * SEQ + scol], &xs[r * 128 + scol]);
  }
  const float* acsr = Acs + (((size_t)b * 64 + h) * 16 + c) * 128;
  float alast = acsr[127];
  if (t < 128) dec[t] = __expf(alast - acsr[t]);
  __syncthreads();

  f32x4_t acc[2][4];
#pragma unroll
  for (int i = 0; i < 2; ++i)
#pragma unroll
    for (int j = 0; j < 4; ++j) acc[i][j] = (f32x4_t){0.f, 0.f, 0.f, 0.f};
#pragma unroll
  for (int ks = 0; ks < 4; ++ks) {
    const int kk = ks * 32 + (lane >> 4) * 8;
    float d8[8];
#pragma unroll
    for (int e = 0; e < 8; ++e) d8[e] = dec[kk + e];
    u16x8_t af[2], bfr[4];
#pragma unroll
    for (int i = 0; i < 2; ++i) {
      u16x8_t raw = *(const u16x8_t*)&xs[(wr * 32 + i * 16 + (lane & 15)) * 128 + kk];
      u16x8_t sc;
#pragma unroll
      for (int e = 0; e < 8; ++e) sc[e] = f2bf(bf2f(raw[e]) * d8[e]);
      af[i] = sc;
    }
#pragma unroll
    for (int j = 0; j < 4; ++j)
      bfr[j] = *(const u16x8_t*)&BTs[(wc * 64 + j * 16 + (lane & 15)) * 128 + kk];
#pragma unroll
    for (int i = 0; i < 2; ++i)
#pragma unroll
      for (int j = 0; j < 4; ++j) acc[i][j] = mfma16(af[i], bfr[j], acc[i][j]);
  }
  unsigned short* so = states + ((((size_t)b * 16 + c) * 64 + h) * 64) * 128;
#pragma unroll
  for (int i = 0; i < 2; ++i) {
    int pbase = wr * 32 + i * 16 + (lane >> 4) * 4;
#pragma unroll
    for (int j = 0; j < 4; ++j) {
      int n = wc * 64 + j * 16 + (lane & 15);
#pragma unroll
      for (int r = 0; r < 4; ++r) so[(size_t)(pbase + r) * 128 + n] = f2bf(acc[i][j][r]);
    }
  }
}

// ------ inter-chunk scan: all 16 chunk loads upfront, vec u16x4 ------
__global__ __launch_bounds__(256) void ssd_scan_kernel(const unsigned short* __restrict__ states,
                                                       const float* __restrict__ cdecay,
                                                       unsigned short* __restrict__ prevb) {
  int blk = blockIdx.x;
  int s = blk & 7, h = (blk >> 3) & 63, b = blk >> 9;
  int t = threadIdx.x;
  const size_t eoff = (size_t)s * 1024 + t * 4;
  const float* cd = cdecay + ((size_t)b * 64 + h) * 16;
  u16x4_t vals[16];
#pragma unroll
  for (int c = 0; c < 16; ++c) {
    const unsigned short* sp = states + (((size_t)(b * 16 + c) * 64 + h) * 64) * 128 + eoff;
    vals[c] = *(const u16x4_t*)sp;
  }
  float carry[4] = {0.f, 0.f, 0.f, 0.f};
#pragma unroll
  for (int c = 0; c < 16; ++c) {
    unsigned short* pp = prevb + (((size_t)(b * 16 + c) * 64 + h) * 64) * 128 + eoff;
    u16x4_t o;
#pragma unroll
    for (int k = 0; k < 4; ++k) o[k] = f2bf(carry[k]);
    *(u16x4_t*)pp = o;
    float d = cd[c];
#pragma unroll
    for (int k = 0; k < 4; ++k) carry[k] = carry[k] * d + bf2f(vals[c][k]);
  }
}

// ---------------- SSD Y = Y_diag + Y_off + D*x (bf16 out) ----------------
__global__ __launch_bounds__(256) void ssd_y_kernel(const unsigned short* __restrict__ xc,
                                                    const unsigned short* __restrict__ xdtT,
                                                    const unsigned short* __restrict__ prevb,
                                                    const float* __restrict__ Acs,
                                                    const float* __restrict__ Dp,
                                                    unsigned short* __restrict__ Y) {
  int blk = blockIdx.x;
  int h = blk & 63, c = (blk >> 6) & 15, b = blk >> 10;
  __shared__ unsigned short Bs[128 * 128];
  __shared__ unsigned short Cs[128 * 128];
  __shared__ unsigned short xs[64 * 128];
  int t = threadIdx.x, lane = t & 63, w = t >> 6, wr = w >> 1, wc = w & 1;
  int srow = t >> 4, scol = (t & 15) * 8;
  const unsigned short* Bg = xc + ((size_t)b * SEQ + c * 128) * DXBC + DINNER;
  const unsigned short* Cg = Bg + DSTATE;
#pragma unroll
  for (int s = 0; s < 8; ++s) {
    int r = s * 16 + srow;
    gload16(&Bg[(size_t)r * DXBC + scol], &Bs[r * 128 + scol]);
    gload16(&Cg[(size_t)r * DXBC + scol], &Cs[r * 128 + scol]);
  }
  const unsigned short* xg = xdtT + (((size_t)b * 64 + h) * 64) * SEQ + c * 128;
#pragma unroll
  for (int s = 0; s < 4; ++s) {
    int r = s * 16 + srow;
    gload16(&xg[(size_t)r * SEQ + scol], &xs[r * 128 + scol]);
  }
  const unsigned short* pg = prevb + ((((size_t)b * 16 + c) * 64 + h) * 64) * 128;
  u16x8_t pf_all[4][2];
#pragma unroll
  for (int ks = 0; ks < 4; ++ks) {
    const int kk = ks * 32 + (lane >> 4) * 8;
#pragma unroll
    for (int j = 0; j < 2; ++j)
      pf_all[ks][j] = *(const u16x8_t*)&pg[(size_t)(wc * 32 + j * 16 + (lane & 15)) * 128 + kk];
  }
  const float* acsr = Acs + (((size_t)b * 64 + h) * 16 + c) * 128;
  __syncthreads();

  f32x4_t cbt[4][4];
#pragma unroll
  for (int i = 0; i < 4; ++i)
#pragma unroll
    for (int j = 0; j < 4; ++j) cbt[i][j] = (f32x4_t){0.f, 0.f, 0.f, 0.f};
#pragma unroll
  for (int ks = 0; ks < 4; ++ks) {
    const int kk = ks * 32 + (lane >> 4) * 8;
    u16x8_t af[4], bfr[4];
#pragma unroll
    for (int i = 0; i < 4; ++i) {
      af[i]  = *(const u16x8_t*)&Bs[(wr * 64 + i * 16 + (lane & 15)) * 128 + kk];
      bfr[i] = *(const u16x8_t*)&Cs[(wc * 64 + i * 16 + (lane & 15)) * 128 + kk];
    }
#pragma unroll
    for (int i = 0; i < 4; ++i)
#pragma unroll
      for (int j = 0; j < 4; ++j) cbt[i][j] = mfma16(af[i], bfr[j], cbt[i][j]);
  }
  __syncthreads();
#pragma unroll
  for (int fi = 0; fi < 4; ++fi) {
#pragma unroll
    for (int fj = 0; fj < 4; ++fj) {
      int i = wc * 64 + fj * 16 + (lane & 15);
      int jb = wr * 64 + fi * 16 + (lane >> 4) * 4;
      float ai = acsr[i];
      u16x4_t m4;
#pragma unroll
      for (int r = 0; r < 4; ++r) {
        int j = jb + r;
        float v = (i >= j) ? cbt[fi][fj][r] * __expf(ai - acsr[j]) : 0.f;
        m4[r] = f2bf(v);
      }
      *(u16x4_t*)&Bs[i * 128 + jb] = m4;
    }
  }
  __syncthreads();

  f32x4_t accY[4][2], accO[4][2];
#pragma unroll
  for (int i = 0; i < 4; ++i)
#pragma unroll
    for (int j = 0; j < 2; ++j) {
      accY[i][j] = (f32x4_t){0.f, 0.f, 0.f, 0.f};
      accO[i][j] = (f32x4_t){0.f, 0.f, 0.f, 0.f};
    }
#pragma unroll
  for (int ks = 0; ks < 4; ++ks) {
    const int kk = ks * 32 + (lane >> 4) * 8;
    u16x8_t af[4], bfr[2], cf[4];
#pragma unroll
    for (int i = 0; i < 4; ++i) {
      af[i] = *(const u16x8_t*)&Bs[(wr * 64 + i * 16 + (lane & 15)) * 128 + kk];
      cf[i] = *(const u16x8_t*)&Cs[(wr * 64 + i * 16 + (lane & 15)) * 128 + kk];
    }
#pragma unroll
    for (int j = 0; j < 2; ++j)
      bfr[j] = *(const u16x8_t*)&xs[(wc * 32 + j * 16 + (lane & 15)) * 128 + kk];
#pragma unroll
    for (int i = 0; i < 4; ++i)
#pragma unroll
      for (int j = 0; j < 2; ++j) {
        accY[i][j] = mfma16(af[i], bfr[j], accY[i][j]);
        accO[i][j] = mfma16(cf[i], pf_all[ks][j], accO[i][j]);
      }
  }
  float Dh = Dp[h];
  unsigned short* Yo = Y + ((size_t)b * SEQ + c * 128) * DINNER + h * 64;
  const unsigned short* xo = xc + ((size_t)b * SEQ + c * 128) * DXBC + h * 64;
#pragma unroll
  for (int fi = 0; fi < 4; ++fi) {
    int ibase = wr * 64 + fi * 16 + (lane >> 4) * 4;
#pragma unroll
    for (int r = 0; r < 4; ++r) {
      int i = ibase + r;
      float esc = __expf(acsr[i]);
#pragma unroll
      for (int fj = 0; fj < 2; ++fj) {
        int p = wc * 32 + fj * 16 + (lane & 15);
        float v = accY[fi][fj][r] + accO[fi][fj][r] * esc + bf2f(xo[(size_t)i * DXBC + p]) * Dh;
        Yo[(size_t)i * DINNER + p] = f2bf(v);
      }
    }
  }
}

// ---------------- gated RMSNorm (bf16 Y) -> bf16, u16x8 vectorized ----------------
__global__ __launch_bounds__(256) void norm_kernel(const unsigned short* __restrict__ Y,
                                                   const unsigned short* __restrict__ zx,
                                                   const float* __restrict__ nw,
                                                   unsigned short* __restrict__ yn) {
  int bl = blockIdx.x;
  const unsigned short* yr = Y + (size_t)bl * DINNER;
  const unsigned short* zr = zx + (size_t)bl * NPAD;
  int t = threadIdx.x;
  int base = t * 16;
  u16x8_t y0 = *(const u16x8_t*)&yr[base], y1 = *(const u16x8_t*)&yr[base + 8];
  u16x8_t z0 = *(const u16x8_t*)&zr[base], z1 = *(const u16x8_t*)&zr[base + 8];
  float vals[16];
  float ss = 0.f;
#pragma unroll
  for (int k = 0; k < 8; ++k) {
    float g = bf2f(y0[k]) * siluf(bf2f(z0[k]));
    vals[k] = g; ss += g * g;
  }
#pragma unroll
  for (int k = 0; k < 8; ++k) {
    float g = bf2f(y1[k]) * siluf(bf2f(z1[k]));
    vals[8 + k] = g; ss += g * g;
  }
#pragma unroll
  for (int o = 32; o > 0; o >>= 1) ss += __shfl_down(ss, o, 64);
  __shared__ float red[4];
  if ((t & 63) == 0) red[t >> 6] = ss;
  __syncthreads();
  float tot = red[0] + red[1] + red[2] + red[3];
  float rs = rsqrtf(tot * (1.f / (float)DINNER) + 1e-5f);
  u16x8_t o0, o1;
#pragma unroll
  for (int k = 0; k < 8; ++k) {
    o0[k] = f2bf(vals[k] * rs * nw[base + k]);
    o1[k] = f2bf(vals[8 + k] * rs * nw[base + 8 + k]);
  }
  *(u16x8_t*)&yn[(size_t)bl * DINNER + base] = o0;
  *(u16x8_t*)&yn[(size_t)bl * DINNER + base + 8] = o1;
}

// ---------------- host ----------------
extern "C" void kernel_launch(void* const* d_in, const int* in_sizes, int n_in,
                              void* d_out, int out_size, void* d_ws, size_t ws_size,
                              hipStream_t stream) {
  const float* u       = (const float*)d_in[0];
  const float* W_in    = (const float*)d_in[1];
  const float* conv_w  = (const float*)d_in[2];
  const float* conv_b  = (const float*)d_in[3];
  const float* dt_bias = (const float*)d_in[4];
  const float* A_log   = (const float*)d_in[5];
  const float* Dv      = (const float*)d_in[6];
  const float* norm_w  = (const float*)d_in[7];
  const float* W_out   = (const float*)d_in[8];
  float* out = (float*)d_out;
  (void)in_sizes; (void)n_in; (void)out_size;

  const size_t SZ_UBF    = (size_t)BL * DMODEL * 2;
  const size_t SZ_WIN    = (size_t)NPAD * DMODEL * 2;
  const size_t SZ_XDTT   = (size_t)NBATCH * NHEADS * HEADDIM * SEQ * 2;
  const size_t SZ_ZX     = (size_t)BL * NPAD * 2;
  const size_t SZ_XC     = (size_t)BL * DXBC * 2;
  const size_t SZ_BT     = (size_t)NBATCH * DSTATE * SEQ * 2;
  const size_t SZ_DTS    = (size_t)NBATCH * NHEADS * SEQ * 4;
  const size_t SZ_ACS    = (size_t)NBATCH * NHEADS * NCHUNK * 128 * 4;
  const size_t SZ_CDEC   = (size_t)NBATCH * NHEADS * NCHUNK * 4;
  const size_t SZ_STATES = (size_t)NBATCH * NCHUNK * NHEADS * HEADDIM * DSTATE * 2;
  const size_t SZ_PREV   = (size_t)NBATCH * NCHUNK * NHEADS * HEADDIM * DSTATE * 2;
  const size_t REGION_A  = SZ_UBF + SZ_WIN;

  char* ws = (char*)d_ws;
  size_t off = 0;
  auto alloc = [&](size_t bytes) { char* p = ws + off; off += (bytes + 255) & ~(size_t)255; return p; };

  char* regionA = alloc(REGION_A);
  unsigned short* zx     = (unsigned short*)alloc(SZ_ZX);
  unsigned short* xc     = (unsigned short*)alloc(SZ_XC);
  unsigned short* BT     = (unsigned short*)alloc(SZ_BT);
  float* dt_soft         = (float*)alloc(SZ_DTS);
  float* Acs             = (float*)alloc(SZ_ACS);
  float* cdecay          = (float*)alloc(SZ_CDEC);
  char* statesYb         = alloc(SZ_STATES);
  char* prevYn           = alloc(SZ_PREV);
  if (off > ws_size) return;

  unsigned short* u_bf    = (unsigned short*)regionA;
  unsigned short* win_bf  = (unsigned short*)(regionA + SZ_UBF);
  unsigned short* xdtT    = (unsigned short*)regionA;
  unsigned short* wout_bf = (unsigned short*)(regionA + SZ_XDTT);
  unsigned short* states  = (unsigned short*)statesYb;
  unsigned short* Yb      = (unsigned short*)statesYb;
  unsigned short* prevb   = (unsigned short*)prevYn;
  unsigned short* yn      = (unsigned short*)prevYn;

  cvt_uw_kernel<<<dim3(GB_U + GB_WIN), dim3(256), 0, stream>>>(u, u_bf, W_in, win_bf);

  // GEMM1: 8-phase template (256^2, BK=64, 544 blocks)
  gemm8p_kernel<true><<<dim3((NPAD / 256) * (BL / 256)), dim3(512), 0, stream>>>(
      u_bf, win_bf, zx, BL, NPAD, DMODEL, NPAD / 256);

  postg1_kernel<<<dim3(GB_WOUT + GB_CONV + GB_DT), dim3(256), 0, stream>>>(
      W_out, wout_bf, zx, conv_w, conv_b, xc, dt_bias, A_log, dt_soft, Acs, cdecay);

  xdtbtr_kernel<<<dim3(GB_XDT + NBATCH * (SEQ / 128)), dim3(256), 0, stream>>>(
      xc, dt_soft, xdtT, BT);

  ssd_states_kernel<<<dim3(NBATCH * NCHUNK * NHEADS), dim3(256), 0, stream>>>(BT, xdtT, Acs, states);
  ssd_scan_kernel<<<dim3(NBATCH * NHEADS * 8), dim3(256), 0, stream>>>(states, cdecay, prevb);
  ssd_y_kernel<<<dim3(NBATCH * NCHUNK * NHEADS), dim3(256), 0, stream>>>(xc, xdtT, prevb, Acs, Dv, Yb);

  norm_kernel<<<dim3(BL), dim3(256), 0, stream>>>(Yb, zx, norm_w, yn);

  // GEMM2: R4 schedule (BM=128, 256 blocks = full device)
  gemm256_kernel<4, false><<<dim3((DMODEL / 256) * (BL / 128)), dim3(512), 0, stream>>>(
      yn, wout_bf, out, BL, DMODEL, DINNER, DMODEL / 256);
}

// Round 12
// 544.755 us; speedup vs baseline: 1.0171x; 1.0171x over previous
//
#include <hip/hip_runtime.h>
#include <cstdint>
#include <cstddef>

#define SEQ     2048
#define NBATCH  2
#define BL      (NBATCH*SEQ)     // 4096
#define DMODEL  2048
#define DINNER  4096
#define DSTATE  128
#define HEADDIM 64
#define NHEADS  64
#define DXBC    4352
#define DPROJ   8512
#define NPAD    8704             // padded D_IN_PROJ (34*256)
#define NCHUNK  16
#define CHUNKL  128

typedef __bf16 bf16x8_t __attribute__((ext_vector_type(8)));
typedef float f32x4_t __attribute__((ext_vector_type(4)));
typedef unsigned short u16x8_t __attribute__((ext_vector_type(8)));
typedef unsigned short u16x4_t __attribute__((ext_vector_type(4)));
typedef __attribute__((address_space(1))) unsigned int as1_u32;
typedef __attribute__((address_space(3))) unsigned int as3_u32;

__device__ __forceinline__ unsigned short f2bf(float f) {
  unsigned u = __builtin_bit_cast(unsigned, f);
  u += 0x7FFFu + ((u >> 16) & 1u);
  return (unsigned short)(u >> 16);
}
__device__ __forceinline__ float bf2f(unsigned short h) {
  unsigned u = ((unsigned)h) << 16;
  return __builtin_bit_cast(float, u);
}
__device__ __forceinline__ void gload16(const void* g, void* l) {
  __builtin_amdgcn_global_load_lds((const as1_u32*)g, (as3_u32*)l, 16, 0, 0);
}
__device__ __forceinline__ f32x4_t mfma16(u16x8_t a, u16x8_t b, f32x4_t c) {
  return __builtin_amdgcn_mfma_f32_16x16x32_bf16(
      __builtin_bit_cast(bf16x8_t, a), __builtin_bit_cast(bf16x8_t, b), c, 0, 0, 0);
}
__device__ __forceinline__ float siluf(float x) { return x / (1.f + __expf(-x)); }

// -------- merged convert: u -> u_bf  |  W_in -> win_bf (zero-padded rows) --------
#define GB_U   (BL * DMODEL / 4 / 256)          // 8192
#define GB_WIN (NPAD * DMODEL / 4 / 256)        // 17408
__global__ __launch_bounds__(256) void cvt_uw_kernel(const float* __restrict__ u,
                                                     unsigned short* __restrict__ u_bf,
                                                     const float* __restrict__ W_in,
                                                     unsigned short* __restrict__ win_bf) {
  int blk = blockIdx.x;
  if (blk < GB_U) {
    int idx = (blk * 256 + threadIdx.x) * 4;
    float4 v = *(const float4*)&u[idx];
    u16x4_t o; o[0] = f2bf(v.x); o[1] = f2bf(v.y); o[2] = f2bf(v.z); o[3] = f2bf(v.w);
    *(u16x4_t*)&u_bf[idx] = o;
  } else {
    int idx = ((blk - GB_U) * 256 + threadIdx.x) * 4;
    int e = idx / DMODEL;
    u16x4_t o;
    if (e < DPROJ) {
      float4 v = *(const float4*)&W_in[idx];
      o[0] = f2bf(v.x); o[1] = f2bf(v.y); o[2] = f2bf(v.z); o[3] = f2bf(v.w);
    } else {
      o[0] = 0; o[1] = 0; o[2] = 0; o[3] = 0;
    }
    *(u16x4_t*)&win_bf[idx] = o;
  }
}

// ---------------- GEMM: C[M][N] = A[M][K] * B[N][K]^T, bf16 in ----------------
// R4-measured-best schedule (179 us, MfmaUtil 35%, 0 bank conflicts; best of
// SEVEN measured schedule variants R3-R11 — do not deviate without A/B data):
// BM = 32*WM (GEMM1: 256, GEMM2: 128), BN = 256, BK = 32, 8 waves (2M x 4N),
// 4-buffer LDS ring, counted vmcnt (2 tiles in flight, never 0 mid-loop),
// XOR swizzle for 64B rows, one barrier per K-tile.
template <int WM, bool BF16OUT>
__global__ __launch_bounds__(512, 2) void gemm256_kernel(const unsigned short* __restrict__ A,
                                                         const unsigned short* __restrict__ B,
                                                         void* __restrict__ Cp,
                                                         int M, int N, int K, int gx) {
  constexpr int BM  = 32 * WM;
  constexpr int AUB = BM * 64;          // A-unit bytes per K-tile
  constexpr int BUB = 16384;            // B-unit bytes (256 rows x 64B)
  constexpr int BUF = AUB + BUB;
  constexpr int LA  = AUB / 8192;       // gload instrs per thread, A unit
  constexpr int LB  = 2;
  constexpr int LT  = LA + LB;          // loads per tile
  __shared__ __attribute__((aligned(16))) char lds[4 * BUF];

  const int nwg = gridDim.x;
  const int q8 = nwg >> 3;
  const int lid = blockIdx.x;
  const int newid = (lid & 7) * q8 + (lid >> 3);     // bijective XCD chunking
  const int band = newid / (gx * 4);
  const int idx  = newid % (gx * 4);
  const int n0 = (idx >> 2) * 256;
  const int m0 = (band * 4 + (idx & 3)) * BM;

  const int t = threadIdx.x, lane = t & 63, w = t >> 6;
  const int wm = w >> 2, wn = w & 3;                 // 2 x 4 waves
  const int NK = K >> 5;
  const int kslot = (lane >> 4) * 16;                // 16B col-slot

  f32x4_t acc[WM][4];
#pragma unroll
  for (int i = 0; i < WM; ++i)
#pragma unroll
    for (int j = 0; j < 4; ++j) acc[i][j] = (f32x4_t){0.f, 0.f, 0.f, 0.f};

  auto stage_unit = [&](int u) {
    if (u >= 2 * NK) return;
    const int Tt = u >> 1;
    char* base = lds + (Tt & 3) * BUF + ((u & 1) ? AUB : 0);
    const unsigned short* G = (u & 1) ? B : A;
    const int g0 = (u & 1) ? n0 : m0;
    const int k0 = Tt << 5;
    if (u & 1) {
#pragma unroll
      for (int i = 0; i < LB; ++i) {
        int o = i * 8192 + t * 16;
        int row = o >> 6;
        int cb = (o & 63) ^ (((row >> 1) & 3) << 4);     // inverse-swizzle source
        gload16(&G[(size_t)(g0 + row) * K + k0 + (cb >> 1)], base + o);
      }
    } else {
#pragma unroll
      for (int i = 0; i < LA; ++i) {
        int o = i * 8192 + t * 16;
        int row = o >> 6;
        int cb = (o & 63) ^ (((row >> 1) & 3) << 4);
        gload16(&G[(size_t)(g0 + row) * K + k0 + (cb >> 1)], base + o);
      }
    }
  };
  auto rdA = [&](int bq, int mr) -> u16x8_t {
    int row = wm * (BM / 2) + mr * 16 + (lane & 15);
    int byte = bq * BUF + row * 64 + (kslot ^ (((row >> 1) & 3) << 4));
    return *(const u16x8_t*)(lds + byte);
  };
  auto rdB = [&](int bq, int nr) -> u16x8_t {
    int row = wn * 64 + nr * 16 + (lane & 15);
    int byte = bq * BUF + AUB + row * 64 + (kslot ^ (((row >> 1) & 3) << 4));
    return *(const u16x8_t*)(lds + byte);
  };

  // prologue: tiles 0,1,2 in flight (3*LT loads)
#pragma unroll
  for (int u = 0; u < 6; ++u) stage_unit(u);

  for (int T = 0; T < NK; ++T) {
    const int bq = T & 3;
    if (T <= NK - 3)      { if constexpr (LT == 4) asm volatile("s_waitcnt vmcnt(8)" ::: "memory");
                            else                   asm volatile("s_waitcnt vmcnt(6)" ::: "memory"); }
    else if (T == NK - 2) { if constexpr (LT == 4) asm volatile("s_waitcnt vmcnt(4)" ::: "memory");
                            else                   asm volatile("s_waitcnt vmcnt(3)" ::: "memory"); }
    else                  asm volatile("s_waitcnt vmcnt(0)" ::: "memory");
    __builtin_amdgcn_s_barrier();
    asm volatile("" ::: "memory");
    __builtin_amdgcn_sched_barrier(0);

    u16x8_t af[WM], bfr[4];
    // phase 0: read A-frags + B 0,1; stage next A-unit; MFMA nr 0,1
#pragma unroll
    for (int mr = 0; mr < WM; ++mr) af[mr] = rdA(bq, mr);
    bfr[0] = rdB(bq, 0);
    bfr[1] = rdB(bq, 1);
    stage_unit(2 * T + 6);
    __builtin_amdgcn_s_setprio(1);
#pragma unroll
    for (int mr = 0; mr < WM; ++mr) {
      acc[mr][0] = mfma16(af[mr], bfr[0], acc[mr][0]);
      acc[mr][1] = mfma16(af[mr], bfr[1], acc[mr][1]);
    }
    __builtin_amdgcn_s_setprio(0);
    // phase 1: read B 2,3; stage next B-unit; MFMA nr 2,3
    bfr[2] = rdB(bq, 2);
    bfr[3] = rdB(bq, 3);
    stage_unit(2 * T + 7);
    __builtin_amdgcn_s_setprio(1);
#pragma unroll
    for (int mr = 0; mr < WM; ++mr) {
      acc[mr][2] = mfma16(af[mr], bfr[2], acc[mr][2]);
      acc[mr][3] = mfma16(af[mr], bfr[3], acc[mr][3]);
    }
    __builtin_amdgcn_s_setprio(0);
  }

  // epilogue
#pragma unroll
  for (int mr = 0; mr < WM; ++mr) {
    const int mbase = m0 + wm * (BM / 2) + mr * 16 + (lane >> 4) * 4;
#pragma unroll
    for (int nr = 0; nr < 4; ++nr) {
      const int n = n0 + wn * 64 + nr * 16 + (lane & 15);
#pragma unroll
      for (int r = 0; r < 4; ++r) {
        if (BF16OUT) ((unsigned short*)Cp)[(size_t)(mbase + r) * N + n] = f2bf(acc[mr][nr][r]);
        else         ((float*)Cp)[(size_t)(mbase + r) * N + n] = acc[mr][nr][r];
      }
    }
  }
}

// -------- merged post-GEMM1: W_out convert | conv+silu | dt softplus+cumsum --------
#define GB_WOUT (DMODEL * DINNER / 4 / 256)     // 8192
#define GB_CONV (BL * (DXBC / 8) / 256)         // 8704
#define GB_DT   (NBATCH * NHEADS * NCHUNK / 2)  // 1024 (2 chunks/block)
__global__ __launch_bounds__(256) void postg1_kernel(const float* __restrict__ W_out,
                                                     unsigned short* __restrict__ wout_bf,
                                                     const unsigned short* __restrict__ zx,
                                                     const float* __restrict__ conv_w,
                                                     const float* __restrict__ conv_b,
                                                     unsigned short* __restrict__ xc,
                                                     const float* __restrict__ dt_bias,
                                                     const float* __restrict__ A_log,
                                                     float* __restrict__ dt_soft,
                                                     float* __restrict__ Acs,
                                                     float* __restrict__ cdecay) {
  __shared__ float sbuf[256];
  int blk = blockIdx.x;
  int t = threadIdx.x;
  if (blk < GB_WOUT) {
    int idx = (blk * 256 + t) * 4;
    float4 v = *(const float4*)&W_out[idx];
    u16x4_t o; o[0] = f2bf(v.x); o[1] = f2bf(v.y); o[2] = f2bf(v.z); o[3] = f2bf(v.w);
    *(u16x4_t*)&wout_bf[idx] = o;
  } else if (blk < GB_WOUT + GB_CONV) {
    int idx = (blk - GB_WOUT) * 256 + t;
    int e8 = (idx % (DXBC / 8)) * 8;
    int bl = idx / (DXBC / 8);
    int l = bl % SEQ, b = bl / SEQ;
    float acc[8];
#pragma unroll
    for (int j = 0; j < 8; ++j) acc[j] = conv_b[e8 + j];
    const unsigned short* zrow = zx + (size_t)b * SEQ * NPAD + DINNER + e8;
#pragma unroll
    for (int wi = 0; wi < 4; ++wi) {
      int ll = l - 3 + wi;
      if (ll >= 0) {
        u16x8_t v = *(const u16x8_t*)(zrow + (size_t)ll * NPAD);
#pragma unroll
        for (int j = 0; j < 8; ++j) acc[j] += bf2f(v[j]) * conv_w[(e8 + j) * 4 + wi];
      }
    }
    u16x8_t o;
#pragma unroll
    for (int j = 0; j < 8; ++j) o[j] = f2bf(siluf(acc[j]));
    *(u16x8_t*)(xc + (size_t)bl * DXBC + e8) = o;
  } else {
    int id = (blk - GB_WOUT - GB_CONV) * 2 + (t >> 7);
    int i = t & 127;
    int c = id & 15, h = (id >> 4) & 63, b = id >> 10;
    int l = c * CHUNKL + i;
    float raw = bf2f(zx[((size_t)b * SEQ + l) * NPAD + (DINNER + DXBC) + h]) + dt_bias[h];
    float dt = (raw > 20.f) ? raw : log1pf(__expf(raw));
    dt_soft[((size_t)b * 64 + h) * SEQ + l] = dt;
    float A = -__expf(A_log[h]);
    float* sb = sbuf + (t >> 7) * 128;
    sb[i] = dt * A;
    __syncthreads();
    for (int ofs = 1; ofs < 128; ofs <<= 1) {
      float v = (i >= ofs) ? sb[i - ofs] : 0.f;
      __syncthreads();
      sb[i] += v;
      __syncthreads();
    }
    float cs = sb[i];
    Acs[(((size_t)b * 64 + h) * 16 + c) * 128 + i] = cs;
    if (i == 127) cdecay[((size_t)b * 64 + h) * 16 + c] = __expf(cs);
  }
}

// -------- merged xdt^T builder | B transpose --------
#define GB_XDT (NBATCH * NHEADS * NCHUNK)       // 2048
__global__ __launch_bounds__(256) void xdtbtr_kernel(const unsigned short* __restrict__ xc,
                                                     const float* __restrict__ dt_soft,
                                                     unsigned short* __restrict__ xdtT,
                                                     unsigned short* __restrict__ BT) {
  __shared__ __attribute__((aligned(16))) char smem[33536];
  int blk = blockIdx.x;
  int t = threadIdx.x;
  if (blk < GB_XDT) {
    int lt = blk & 15, h = (blk >> 4) & 63, b = blk >> 10;
    unsigned short (*tile)[66] = (unsigned short(*)[66])smem;
    float* dts = (float*)(smem + 16896);
    const unsigned short* xg = xc + ((size_t)b * SEQ + lt * 128) * DXBC + h * 64;
#pragma unroll
    for (int k = 0; k < 32; ++k) {
      int idx = t + k * 256;
      int row = idx >> 6, col = idx & 63;
      tile[row][col] = xg[(size_t)row * DXBC + col];
    }
    if (t < 128) dts[t] = dt_soft[((size_t)b * 64 + h) * SEQ + lt * 128 + t];
    __syncthreads();
    unsigned short* xo = xdtT + (((size_t)b * 64 + h) * 64) * SEQ + lt * 128;
#pragma unroll
    for (int k = 0; k < 32; ++k) {
      int idx = t + k * 256;
      int p = idx >> 7, j = idx & 127;
      xo[(size_t)p * SEQ + j] = f2bf(bf2f(tile[j][p]) * dts[j]);
    }
  } else {
    int bb = blk - GB_XDT;
    int lt = bb & 15, b = bb >> 4;
    unsigned short (*tile)[129] = (unsigned short(*)[129])smem;
    const unsigned short* src = xc + ((size_t)b * SEQ + lt * 128) * DXBC + DINNER;
#pragma unroll
    for (int k = 0; k < 64; ++k) {
      int idx = t + k * 256;
      int j = idx >> 7, n = idx & 127;
      tile[j][n] = src[(size_t)j * DXBC + n];
    }
    __syncthreads();
    unsigned short* dst = BT + (size_t)b * 128 * SEQ + lt * 128;
#pragma unroll
    for (int k = 0; k < 64; ++k) {
      int idx = t + k * 256;
      int n = idx >> 7, j = idx & 127;
      dst[(size_t)n * SEQ + j] = tile[j][n];
    }
  }
}

// -------- SSD per-chunk states (bf16 out): states[b][c][h][p][n] --------
__global__ __launch_bounds__(256) void ssd_states_kernel(const unsigned short* __restrict__ BT,
                                                         const unsigned short* __restrict__ xdtT,
                                                         const float* __restrict__ Acs,
                                                         unsigned short* __restrict__ states) {
  int blk = blockIdx.x;
  int h = blk & 63, c = (blk >> 6) & 15, b = blk >> 10;
  __shared__ unsigned short BTs[128 * 128];
  __shared__ unsigned short xs[64 * 128];
  __shared__ float dec[128];
  int t = threadIdx.x, lane = t & 63, w = t >> 6, wr = w >> 1, wc = w & 1;
  int srow = t >> 4, scol = (t & 15) * 8;
  const unsigned short* BTb = BT + (size_t)b * 128 * SEQ + c * 128;
#pragma unroll
  for (int s = 0; s < 8; ++s) {
    int r = s * 16 + srow;
    gload16(&BTb[(size_t)r * SEQ + scol], &BTs[r * 128 + scol]);
  }
  const unsigned short* xb = xdtT + (((size_t)b * 64 + h) * 64) * SEQ + c * 128;
#pragma unroll
  for (int s = 0; s < 4; ++s) {
    int r = s * 16 + srow;
    gload16(&xb[(size_t)r * SEQ + scol], &xs[r * 128 + scol]);
  }
  const float* acsr = Acs + (((size_t)b * 64 + h) * 16 + c) * 128;
  float alast = acsr[127];
  if (t < 128) dec[t] = __expf(alast - acsr[t]);
  __syncthreads();

  f32x4_t acc[2][4];
#pragma unroll
  for (int i = 0; i < 2; ++i)
#pragma unroll
    for (int j = 0; j < 4; ++j) acc[i][j] = (f32x4_t){0.f, 0.f, 0.f, 0.f};
#pragma unroll
  for (int ks = 0; ks < 4; ++ks) {
    const int kk = ks * 32 + (lane >> 4) * 8;
    float d8[8];
#pragma unroll
    for (int e = 0; e < 8; ++e) d8[e] = dec[kk + e];
    u16x8_t af[2], bfr[4];
#pragma unroll
    for (int i = 0; i < 2; ++i) {
      u16x8_t raw = *(const u16x8_t*)&xs[(wr * 32 + i * 16 + (lane & 15)) * 128 + kk];
      u16x8_t sc;
#pragma unroll
      for (int e = 0; e < 8; ++e) sc[e] = f2bf(bf2f(raw[e]) * d8[e]);
      af[i] = sc;
    }
#pragma unroll
    for (int j = 0; j < 4; ++j)
      bfr[j] = *(const u16x8_t*)&BTs[(wc * 64 + j * 16 + (lane & 15)) * 128 + kk];
#pragma unroll
    for (int i = 0; i < 2; ++i)
#pragma unroll
      for (int j = 0; j < 4; ++j) acc[i][j] = mfma16(af[i], bfr[j], acc[i][j]);
  }
  unsigned short* so = states + ((((size_t)b * 16 + c) * 64 + h) * 64) * 128;
#pragma unroll
  for (int i = 0; i < 2; ++i) {
    int pbase = wr * 32 + i * 16 + (lane >> 4) * 4;
#pragma unroll
    for (int j = 0; j < 4; ++j) {
      int n = wc * 64 + j * 16 + (lane & 15);
#pragma unroll
      for (int r = 0; r < 4; ++r) so[(size_t)(pbase + r) * 128 + n] = f2bf(acc[i][j][r]);
    }
  }
}

// ------ inter-chunk scan: all 16 chunk loads upfront, vec u16x4 ------
__global__ __launch_bounds__(256) void ssd_scan_kernel(const unsigned short* __restrict__ states,
                                                       const float* __restrict__ cdecay,
                                                       unsigned short* __restrict__ prevb) {
  int blk = blockIdx.x;
  int s = blk & 7, h = (blk >> 3) & 63, b = blk >> 9;
  int t = threadIdx.x;
  const size_t eoff = (size_t)s * 1024 + t * 4;
  const float* cd = cdecay + ((size_t)b * 64 + h) * 16;
  u16x4_t vals[16];
#pragma unroll
  for (int c = 0; c < 16; ++c) {
    const unsigned short* sp = states + (((size_t)(b * 16 + c) * 64 + h) * 64) * 128 + eoff;
    vals[c] = *(const u16x4_t*)sp;
  }
  float carry[4] = {0.f, 0.f, 0.f, 0.f};
#pragma unroll
  for (int c = 0; c < 16; ++c) {
    unsigned short* pp = prevb + (((size_t)(b * 16 + c) * 64 + h) * 64) * 128 + eoff;
    u16x4_t o;
#pragma unroll
    for (int k = 0; k < 4; ++k) o[k] = f2bf(carry[k]);
    *(u16x4_t*)pp = o;
    float d = cd[c];
#pragma unroll
    for (int k = 0; k < 4; ++k) carry[k] = carry[k] * d + bf2f(vals[c][k]);
  }
}

// ---------------- SSD Y = Y_diag + Y_off + D*x (bf16 out) ----------------
__global__ __launch_bounds__(256) void ssd_y_kernel(const unsigned short* __restrict__ xc,
                                                    const unsigned short* __restrict__ xdtT,
                                                    const unsigned short* __restrict__ prevb,
                                                    const float* __restrict__ Acs,
                                                    const float* __restrict__ Dp,
                                                    unsigned short* __restrict__ Y) {
  int blk = blockIdx.x;
  int h = blk & 63, c = (blk >> 6) & 15, b = blk >> 10;
  __shared__ unsigned short Bs[128 * 128];
  __shared__ unsigned short Cs[128 * 128];
  __shared__ unsigned short xs[64 * 128];
  int t = threadIdx.x, lane = t & 63, w = t >> 6, wr = w >> 1, wc = w & 1;
  int srow = t >> 4, scol = (t & 15) * 8;
  const unsigned short* Bg = xc + ((size_t)b * SEQ + c * 128) * DXBC + DINNER;
  const unsigned short* Cg = Bg + DSTATE;
#pragma unroll
  for (int s = 0; s < 8; ++s) {
    int r = s * 16 + srow;
    gload16(&Bg[(size_t)r * DXBC + scol], &Bs[r * 128 + scol]);
    gload16(&Cg[(size_t)r * DXBC + scol], &Cs[r * 128 + scol]);
  }
  const unsigned short* xg = xdtT + (((size_t)b * 64 + h) * 64) * SEQ + c * 128;
#pragma unroll
  for (int s = 0; s < 4; ++s) {
    int r = s * 16 + srow;
    gload16(&xg[(size_t)r * SEQ + scol], &xs[r * 128 + scol]);
  }
  const unsigned short* pg = prevb + ((((size_t)b * 16 + c) * 64 + h) * 64) * 128;
  u16x8_t pf_all[4][2];
#pragma unroll
  for (int ks = 0; ks < 4; ++ks) {
    const int kk = ks * 32 + (lane >> 4) * 8;
#pragma unroll
    for (int j = 0; j < 2; ++j)
      pf_all[ks][j] = *(const u16x8_t*)&pg[(size_t)(wc * 32 + j * 16 + (lane & 15)) * 128 + kk];
  }
  const float* acsr = Acs + (((size_t)b * 64 + h) * 16 + c) * 128;
  __syncthreads();

  f32x4_t cbt[4][4];
#pragma unroll
  for (int i = 0; i < 4; ++i)
#pragma unroll
    for (int j = 0; j < 4; ++j) cbt[i][j] = (f32x4_t){0.f, 0.f, 0.f, 0.f};
#pragma unroll
  for (int ks = 0; ks < 4; ++ks) {
    const int kk = ks * 32 + (lane >> 4) * 8;
    u16x8_t af[4], bfr[4];
#pragma unroll
    for (int i = 0; i < 4; ++i) {
      af[i]  = *(const u16x8_t*)&Bs[(wr * 64 + i * 16 + (lane & 15)) * 128 + kk];
      bfr[i] = *(const u16x8_t*)&Cs[(wc * 64 + i * 16 + (lane & 15)) * 128 + kk];
    }
#pragma unroll
    for (int i = 0; i < 4; ++i)
#pragma unroll
      for (int j = 0; j < 4; ++j) cbt[i][j] = mfma16(af[i], bfr[j], cbt[i][j]);
  }
  __syncthreads();
#pragma unroll
  for (int fi = 0; fi < 4; ++fi) {
#pragma unroll
    for (int fj = 0; fj < 4; ++fj) {
      int i = wc * 64 + fj * 16 + (lane & 15);
      int jb = wr * 64 + fi * 16 + (lane >> 4) * 4;
      float ai = acsr[i];
      u16x4_t m4;
#pragma unroll
      for (int r = 0; r < 4; ++r) {
        int j = jb + r;
        float v = (i >= j) ? cbt[fi][fj][r] * __expf(ai - acsr[j]) : 0.f;
        m4[r] = f2bf(v);
      }
      *(u16x4_t*)&Bs[i * 128 + jb] = m4;
    }
  }
  __syncthreads();

  f32x4_t accY[4][2], accO[4][2];
#pragma unroll
  for (int i = 0; i < 4; ++i)
#pragma unroll
    for (int j = 0; j < 2; ++j) {
      accY[i][j] = (f32x4_t){0.f, 0.f, 0.f, 0.f};
      accO[i][j] = (f32x4_t){0.f, 0.f, 0.f, 0.f};
    }
#pragma unroll
  for (int ks = 0; ks < 4; ++ks) {
    const int kk = ks * 32 + (lane >> 4) * 8;
    u16x8_t af[4], bfr[2], cf[4];
#pragma unroll
    for (int i = 0; i < 4; ++i) {
      af[i] = *(const u16x8_t*)&Bs[(wr * 64 + i * 16 + (lane & 15)) * 128 + kk];
      cf[i] = *(const u16x8_t*)&Cs[(wr * 64 + i * 16 + (lane & 15)) * 128 + kk];
    }
#pragma unroll
    for (int j = 0; j < 2; ++j)
      bfr[j] = *(const u16x8_t*)&xs[(wc * 32 + j * 16 + (lane & 15)) * 128 + kk];
#pragma unroll
    for (int i = 0; i < 4; ++i)
#pragma unroll
      for (int j = 0; j < 2; ++j) {
        accY[i][j] = mfma16(af[i], bfr[j], accY[i][j]);
        accO[i][j] = mfma16(cf[i], pf_all[ks][j], accO[i][j]);
      }
  }
  float Dh = Dp[h];
  unsigned short* Yo = Y + ((size_t)b * SEQ + c * 128) * DINNER + h * 64;
  const unsigned short* xo = xc + ((size_t)b * SEQ + c * 128) * DXBC + h * 64;
#pragma unroll
  for (int fi = 0; fi < 4; ++fi) {
    int ibase = wr * 64 + fi * 16 + (lane >> 4) * 4;
#pragma unroll
    for (int r = 0; r < 4; ++r) {
      int i = ibase + r;
      float esc = __expf(acsr[i]);
#pragma unroll
      for (int fj = 0; fj < 2; ++fj) {
        int p = wc * 32 + fj * 16 + (lane & 15);
        float v = accY[fi][fj][r] + accO[fi][fj][r] * esc + bf2f(xo[(size_t)i * DXBC + p]) * Dh;
        Yo[(size_t)i * DINNER + p] = f2bf(v);
      }
    }
  }
}

// ---------------- gated RMSNorm (bf16 Y) -> bf16, u16x8 vectorized ----------------
__global__ __launch_bounds__(256) void norm_kernel(const unsigned short* __restrict__ Y,
                                                   const unsigned short* __restrict__ zx,
                                                   const float* __restrict__ nw,
                                                   unsigned short* __restrict__ yn) {
  int bl = blockIdx.x;
  const unsigned short* yr = Y + (size_t)bl * DINNER;
  const unsigned short* zr = zx + (size_t)bl * NPAD;
  int t = threadIdx.x;
  int base = t * 16;
  u16x8_t y0 = *(const u16x8_t*)&yr[base], y1 = *(const u16x8_t*)&yr[base + 8];
  u16x8_t z0 = *(const u16x8_t*)&zr[base], z1 = *(const u16x8_t*)&zr[base + 8];
  float vals[16];
  float ss = 0.f;
#pragma unroll
  for (int k = 0; k < 8; ++k) {
    float g = bf2f(y0[k]) * siluf(bf2f(z0[k]));
    vals[k] = g; ss += g * g;
  }
#pragma unroll
  for (int k = 0; k < 8; ++k) {
    float g = bf2f(y1[k]) * siluf(bf2f(z1[k]));
    vals[8 + k] = g; ss += g * g;
  }
#pragma unroll
  for (int o = 32; o > 0; o >>= 1) ss += __shfl_down(ss, o, 64);
  __shared__ float red[4];
  if ((t & 63) == 0) red[t >> 6] = ss;
  __syncthreads();
  float tot = red[0] + red[1] + red[2] + red[3];
  float rs = rsqrtf(tot * (1.f / (float)DINNER) + 1e-5f);
  u16x8_t o0, o1;
#pragma unroll
  for (int k = 0; k < 8; ++k) {
    o0[k] = f2bf(vals[k] * rs * nw[base + k]);
    o1[k] = f2bf(vals[8 + k] * rs * nw[base + 8 + k]);
  }
  *(u16x8_t*)&yn[(size_t)bl * DINNER + base] = o0;
  *(u16x8_t*)&yn[(size_t)bl * DINNER + base + 8] = o1;
}

// ---------------- host ----------------
extern "C" void kernel_launch(void* const* d_in, const int* in_sizes, int n_in,
                              void* d_out, int out_size, void* d_ws, size_t ws_size,
                              hipStream_t stream) {
  const float* u       = (const float*)d_in[0];
  const float* W_in    = (const float*)d_in[1];
  const float* conv_w  = (const float*)d_in[2];
  const float* conv_b  = (const float*)d_in[3];
  const float* dt_bias = (const float*)d_in[4];
  const float* A_log   = (const float*)d_in[5];
  const float* Dv      = (const float*)d_in[6];
  const float* norm_w  = (const float*)d_in[7];
  const float* W_out   = (const float*)d_in[8];
  float* out = (float*)d_out;
  (void)in_sizes; (void)n_in; (void)out_size;

  const size_t SZ_UBF    = (size_t)BL * DMODEL * 2;
  const size_t SZ_WIN    = (size_t)NPAD * DMODEL * 2;
  const size_t SZ_XDTT   = (size_t)NBATCH * NHEADS * HEADDIM * SEQ * 2;
  const size_t SZ_ZX     = (size_t)BL * NPAD * 2;
  const size_t SZ_XC     = (size_t)BL * DXBC * 2;
  const size_t SZ_BT     = (size_t)NBATCH * DSTATE * SEQ * 2;
  const size_t SZ_DTS    = (size_t)NBATCH * NHEADS * SEQ * 4;
  const size_t SZ_ACS    = (size_t)NBATCH * NHEADS * NCHUNK * 128 * 4;
  const size_t SZ_CDEC   = (size_t)NBATCH * NHEADS * NCHUNK * 4;
  const size_t SZ_STATES = (size_t)NBATCH * NCHUNK * NHEADS * HEADDIM * DSTATE * 2;
  const size_t SZ_PREV   = (size_t)NBATCH * NCHUNK * NHEADS * HEADDIM * DSTATE * 2;
  const size_t REGION_A  = SZ_UBF + SZ_WIN;

  char* ws = (char*)d_ws;
  size_t off = 0;
  auto alloc = [&](size_t bytes) { char* p = ws + off; off += (bytes + 255) & ~(size_t)255; return p; };

  char* regionA = alloc(REGION_A);
  unsigned short* zx     = (unsigned short*)alloc(SZ_ZX);
  unsigned short* xc     = (unsigned short*)alloc(SZ_XC);
  unsigned short* BT     = (unsigned short*)alloc(SZ_BT);
  float* dt_soft         = (float*)alloc(SZ_DTS);
  float* Acs             = (float*)alloc(SZ_ACS);
  float* cdecay          = (float*)alloc(SZ_CDEC);
  char* statesYb         = alloc(SZ_STATES);
  char* prevYn           = alloc(SZ_PREV);
  if (off > ws_size) return;

  unsigned short* u_bf    = (unsigned short*)regionA;
  unsigned short* win_bf  = (unsigned short*)(regionA + SZ_UBF);
  unsigned short* xdtT    = (unsigned short*)regionA;
  unsigned short* wout_bf = (unsigned short*)(regionA + SZ_XDTT);
  unsigned short* states  = (unsigned short*)statesYb;
  unsigned short* Yb      = (unsigned short*)statesYb;
  unsigned short* prevb   = (unsigned short*)prevYn;
  unsigned short* yn      = (unsigned short*)prevYn;

  cvt_uw_kernel<<<dim3(GB_U + GB_WIN), dim3(256), 0, stream>>>(u, u_bf, W_in, win_bf);

  // GEMM1: R4 schedule (BM=256, 544 blocks) — measured best of 7 variants
  gemm256_kernel<8, true><<<dim3((NPAD / 256) * (BL / 256)), dim3(512), 0, stream>>>(
      u_bf, win_bf, zx, BL, NPAD, DMODEL, NPAD / 256);

  postg1_kernel<<<dim3(GB_WOUT + GB_CONV + GB_DT), dim3(256), 0, stream>>>(
      W_out, wout_bf, zx, conv_w, conv_b, xc, dt_bias, A_log, dt_soft, Acs, cdecay);

  xdtbtr_kernel<<<dim3(GB_XDT + NBATCH * (SEQ / 128)), dim3(256), 0, stream>>>(
      xc, dt_soft, xdtT, BT);

  ssd_states_kernel<<<dim3(NBATCH * NCHUNK * NHEADS), dim3(256), 0, stream>>>(BT, xdtT, Acs, states);
  ssd_scan_kernel<<<dim3(NBATCH * NHEADS * 8), dim3(256), 0, stream>>>(states, cdecay, prevb);
  ssd_y_kernel<<<dim3(NBATCH * NCHUNK * NHEADS), dim3(256), 0, stream>>>(xc, xdtT, prevb, Acs, Dv, Yb);

  norm_kernel<<<dim3(BL), dim3(256), 0, stream>>>(Yb, zx, norm_w, yn);

  // GEMM2: R4 schedule (BM=128, 256 blocks = full device)
  gemm256_kernel<4, false><<<dim3((DMODEL / 256) * (BL / 128)), dim3(512), 0, stream>>>(
      yn, wout_bf, out, BL, DMODEL, DINNER, DMODEL / 256);
}